// Round 10
// baseline (449.084 us; speedup 1.0000x reference)
//
#include <hip/hip_runtime.h>
#include <stdint.h>

#define N_NODES 50000
#define N_EDGES 1600000
#define IN_CH   128
#define OUT_CH  64
#define CAP     72            // per-node slot capacity; P(Poisson(32) >= 72) ~ 6e-18
#define NBUCKET 196           // bucket = dst >> 8  (49999>>8 = 195)
#define BCAP    9216          // per-bucket edge capacity; mean 8163, +11 sigma
#define BIN_BLOCKS 1000
#define EPB     1600          // edges per bin block; 1000*1600 = 1.6M exactly
#define BKCAP   32            // per-(block,bucket) LDS stage cap; mean 8.2, fallback safe
#define NODES_PAD (NBUCKET * 256)   // 50176

// ---------- small helpers ----------
__device__ __forceinline__ unsigned int f2bf(float f) {
    unsigned int u = __float_as_uint(f);
    u += 0x7fffu + ((u >> 16) & 1u);   // round-to-nearest-even
    return u >> 16;
}
__device__ __forceinline__ float lrelu(float v, float s) { return v > 0.f ? v : s * v; }

#define POOL_SCALE 268435456.0f        // 2^28 fixed-point for packed alpha-sum
#define POOL_MASK  ((1ull << 40) - 1ull)

// ---------- K1: H = x @ W[i] (bf16 out), a_s, a_d; block 0 zeroes gcur ----------
__global__ __launch_bounds__(256, 1) void k_gemm(
    const float* __restrict__ x, const float* __restrict__ W,
    const float* __restrict__ att_src, const float* __restrict__ att_dst,
    unsigned short* __restrict__ H, float* __restrict__ a_s, float* __restrict__ a_d,
    int* __restrict__ gcur)
{
    __shared__ __align__(16) unsigned char smem[64 * 264 * 2];  // 33792 B, overlaid
    float* sx = (float*)smem;                   // [64][129] fp32 x tile
    unsigned short* sh = (unsigned short*)smem; // [64][264] bf16 H tile

    const int tid  = threadIdx.x;
    const int lane = tid & 63;
    const int wv   = __builtin_amdgcn_readfirstlane(tid >> 6);
    const int row0 = blockIdx.x * 64;

    if (blockIdx.x == 0 && tid < NBUCKET) gcur[tid] = 0;   // replaces memset dispatch

    for (int idx = tid; idx < 64 * 32; idx += 256) {
        int r = idx >> 5, c4 = idx & 31;
        int row = row0 + r;
        float4 v = make_float4(0.f, 0.f, 0.f, 0.f);
        if (row < N_NODES) v = ((const float4*)(x + (size_t)row * IN_CH))[c4];
        float* p = sx + r * 129 + c4 * 4;
        p[0] = v.x; p[1] = v.y; p[2] = v.z; p[3] = v.w;
    }
    __syncthreads();

    float acc[64];
#pragma unroll
    for (int c = 0; c < 64; ++c) acc[c] = 0.f;

    const float* Wl = W + (size_t)wv * IN_CH * OUT_CH;   // uniform -> s_load
    const float* xrow = sx + lane * 129;
#pragma unroll 2
    for (int k = 0; k < IN_CH; ++k) {
        float xv = xrow[k];
        const float* Wk = Wl + k * OUT_CH;
#pragma unroll
        for (int c = 0; c < 64; ++c) acc[c] = fmaf(xv, Wk[c], acc[c]);
    }

    const float* As = att_src + wv * OUT_CH;
    const float* Ad = att_dst + wv * OUT_CH;
    float asv = 0.f, adv = 0.f;
#pragma unroll
    for (int c = 0; c < 64; ++c) { asv = fmaf(acc[c], As[c], asv); adv = fmaf(acc[c], Ad[c], adv); }
    int row = row0 + lane;
    if (row < N_NODES) { a_s[row * 4 + wv] = asv; a_d[row * 4 + wv] = adv; }

    __syncthreads();
    unsigned int* shp = (unsigned int*)sh;
#pragma unroll
    for (int c2 = 0; c2 < 32; ++c2) {
        unsigned int lo = f2bf(acc[c2 * 2]);
        unsigned int hi = f2bf(acc[c2 * 2 + 1]);
        shp[lane * 132 + wv * 32 + c2] = lo | (hi << 16);
    }
    __syncthreads();

    for (int idx = tid; idx < 64 * 32; idx += 256) {
        int r = idx >> 5, c8 = idx & 31;
        int row2 = row0 + r;
        if (row2 < N_NODES) {
            const uint4* srcp = (const uint4*)(sh + r * 264);
            ((uint4*)(H + (size_t)row2 * 256))[c8] = srcp[c8];
        }
    }
}

// ---------- K2: single-pass bin into 196 dst-buckets via LDS staging ----------
__global__ __launch_bounds__(256) void k_bin(
    const int* __restrict__ ei, int* __restrict__ gcur,
    unsigned int* __restrict__ binned)
{
    __shared__ int lcnt[NBUCKET];
    __shared__ int lbase[NBUCKET];
    __shared__ unsigned int stage[BKCAP * 256];   // [pos][bk], bank = bk%32
    const int tid = threadIdx.x;
    const int start = blockIdx.x * EPB;

    // self-detect int64 vs int32: odd 32-bit words all zero iff int64
    int probe = ei[2 * (start + tid) + 1];
    const int is64 = (__ballot(probe != 0) == 0ull) ? 1 : 0;

    for (int i = tid; i < NBUCKET; i += 256) lcnt[i] = 0;
    __syncthreads();

    for (int e = start + tid; e < start + EPB; e += 256) {
        int s = is64 ? ei[2 * (long long)e] : ei[e];
        int d = is64 ? ei[2 * ((long long)N_EDGES + e)] : ei[N_EDGES + e];
        int bk = d >> 8;
        unsigned int pk = ((unsigned int)s << 16) | (unsigned int)d;
        int pos = atomicAdd(&lcnt[bk], 1);
        if (pos < BKCAP) {
            stage[pos * 256 + bk] = pk;
        } else {                                   // ~3e-5 probability total: correct fallback
            int gi = atomicAdd(&gcur[bk], 1);
            if (gi < BCAP) binned[bk * BCAP + gi] = pk;
        }
    }
    __syncthreads();

    for (int i = tid; i < NBUCKET; i += 256) {
        int c = lcnt[i];
        if (c > BKCAP) c = BKCAP;
        lbase[i] = c ? atomicAdd(&gcur[i], c) : 0;
        lcnt[i] = c;
    }
    __syncthreads();

    for (int i = tid; i < BKCAP * 256; i += 256) {
        int pos = i >> 8, bk = i & 255;
        if (bk < NBUCKET && pos < lcnt[bk])
            binned[bk * BCAP + lbase[bk] + pos] = stage[i];
    }
}

// ---------- K3: per-bucket placement in LDS + PER-NODE SRC SORT, coalesced flush ----------
__global__ __launch_bounds__(256) void k_bucket(
    const unsigned int* __restrict__ binned, const int* __restrict__ gcur,
    unsigned short* __restrict__ slot, int* __restrict__ cnt_dst,
    unsigned long long* __restrict__ pool)
{
    __shared__ unsigned short sl[256 * CAP];   // 36864 B slot tile (256 nodes)
    __shared__ int cnt[256];
    const int b = blockIdx.x;
    const int tid = threadIdx.x;
    cnt[tid] = 0;
    int pidx = b * 256 + tid;
    if (pidx < N_NODES) pool[pidx] = 0ull;     // replaces memset dispatch
    __syncthreads();

    int total = gcur[b];
    if (total > BCAP) total = BCAP;
    const unsigned int* src = binned + b * BCAP;
    for (int i = tid; i < total; i += 256) {
        unsigned int p = src[i];                 // coalesced
        int local = p & 255;                     // d & 255 (bucket = d>>8)
        int pos = atomicAdd(&cnt[local], 1);     // LDS atomic — no fabric traffic
        if (pos < CAP) sl[local * CAP + pos] = (unsigned short)(p >> 16);
    }
    __syncthreads();

    // per-node insertion sort by src: gives k_gather waves an ascending-src
    // sweep so co-resident waves share a small moving H window (L2 locality)
    {
        int n = cnt[tid];
        if (n > CAP) n = CAP;
        unsigned short* a = sl + tid * CAP;
        for (int i = 1; i < n; ++i) {
            unsigned short key = a[i];
            int j = i - 1;
            while (j >= 0 && a[j] > key) { a[j + 1] = a[j]; --j; }
            a[j + 1] = key;
        }
    }
    __syncthreads();

    uint4* g = (uint4*)(slot + (size_t)b * 256 * CAP);
    const uint4* l = (const uint4*)sl;
    for (int i = tid; i < 256 * CAP * 2 / 16; i += 256) g[i] = l[i];
    cnt_dst[b * 256 + tid] = cnt[tid];
}

// ---------- K4: per-dst-node gather, 16-edge MLP batches, fused src-pooling ----------
__global__ __launch_bounds__(256) void k_gather(
    const unsigned short* __restrict__ H, const unsigned short* __restrict__ slot,
    const int* __restrict__ cnt_dst,
    const float* __restrict__ a_s, const float* __restrict__ a_d,
    const float* __restrict__ bias, unsigned long long* __restrict__ pool,
    float* __restrict__ out)
{
    const int lane = threadIdx.x & 63;
    const int wv = __builtin_amdgcn_readfirstlane(threadIdx.x >> 6);
    const int node = blockIdx.x * 4 + wv;          // grid*4 == N_NODES exactly
    int deg = __builtin_amdgcn_readfirstlane(cnt_dst[node]);
    if (deg > CAP) deg = CAP;
    const int layer = lane >> 4;

    const float adv = a_d[node * 4 + layer];
    const float4* as4p = (const float4*)a_s;

    float ax = 0.f, ay = 0.f, az = 0.f, aw = 0.f, sumExp = 0.f;
    const uint2* Hp = (const uint2*)H + lane;      // lane's 8B of each 512B row

    auto body = [&](unsigned int s) {
        float4 as4 = as4p[s];                      // wave-uniform -> s_load_dwordx4
        float asv = (layer & 2) ? ((layer & 1) ? as4.w : as4.z)
                                : ((layer & 1) ? as4.y : as4.x);
        float t = asv + adv;
        float ew = __expf(fmaxf(t, 0.2f * t));     // lrelu+exp, 3 VALU
        uint2 hv = Hp[(size_t)s * 64];             // 512B/wave coalesced
        ax = fmaf(ew, __uint_as_float(hv.x << 16), ax);
        ay = fmaf(ew, __uint_as_float(hv.x & 0xffff0000u), ay);
        az = fmaf(ew, __uint_as_float(hv.y << 16), az);
        aw = fmaf(ew, __uint_as_float(hv.y & 0xffff0000u), aw);
        sumExp += ew;
    };

    const unsigned int* sp = (const unsigned int*)(slot + (size_t)node * CAP);
    const int npair = deg >> 1;
    int j2 = 0;
    for (; j2 + 8 <= npair; j2 += 8) {             // 16 edges in flight
        uint4 pa = *(const uint4*)(sp + j2);
        uint4 pb = *(const uint4*)(sp + j2 + 4);
        body(pa.x & 0xffffu); body(pa.x >> 16);
        body(pa.y & 0xffffu); body(pa.y >> 16);
        body(pa.z & 0xffffu); body(pa.z >> 16);
        body(pa.w & 0xffffu); body(pa.w >> 16);
        body(pb.x & 0xffffu); body(pb.x >> 16);
        body(pb.y & 0xffffu); body(pb.y >> 16);
        body(pb.z & 0xffffu); body(pb.z >> 16);
        body(pb.w & 0xffffu); body(pb.w >> 16);
    }
    for (; j2 + 4 <= npair; j2 += 4) {             // 8 edges
        uint4 p4 = *(const uint4*)(sp + j2);
        body(p4.x & 0xffffu); body(p4.x >> 16);
        body(p4.y & 0xffffu); body(p4.y >> 16);
        body(p4.z & 0xffffu); body(p4.z >> 16);
        body(p4.w & 0xffffu); body(p4.w >> 16);
    }
    for (; j2 < npair; ++j2) {
        unsigned int pr = sp[j2];
        body(pr & 0xffffu); body(pr >> 16);
    }
    if (deg & 1) body(sp[npair] & 0xffffu);

    float inv = 1.0f / (sumExp + 1e-16f);          // normalize once per node
    float4 b = ((const float4*)bias)[lane];
    float v0 = lrelu(fmaf(ax, inv, b.x), 0.01f);
    float v1 = lrelu(fmaf(ay, inv, b.y), 0.01f);
    float v2 = lrelu(fmaf(az, inv, b.z), 0.01f);
    float v3 = lrelu(fmaf(aw, inv, b.w), 0.01f);
    // sum the 4 layers: partners are lane ^ 16, lane ^ 32
    v0 += __shfl_xor(v0, 16); v0 += __shfl_xor(v0, 32);
    v1 += __shfl_xor(v1, 16); v1 += __shfl_xor(v1, 32);
    v2 += __shfl_xor(v2, 16); v2 += __shfl_xor(v2, 32);
    v3 += __shfl_xor(v3, 16); v3 += __shfl_xor(v3, 32);

    if (lane < 16) {
        ((float4*)(out + (size_t)node * 64))[lane] = make_float4(v0, v1, v2, v3);
    }

    // phase B: fused pooling — one packed u64 atomic per edge
    float i0 = 1.0f / (__shfl(sumExp,  0) + 1e-16f);
    float i1 = 1.0f / (__shfl(sumExp, 16) + 1e-16f);
    float i2 = 1.0f / (__shfl(sumExp, 32) + 1e-16f);
    float i3 = 1.0f / (__shfl(sumExp, 48) + 1e-16f);
    float4 ad4 = ((const float4*)a_d)[node];       // wave-uniform
    const unsigned short* s16 = slot + (size_t)node * CAP;
    for (int jj = lane; jj < deg; jj += 64) {
        int s = s16[jj];                           // coalesced 2B/lane
        float4 as4 = as4p[s];                      // 16B/lane gather (L2-hot)
        float t0 = as4.x + ad4.x, t1 = as4.y + ad4.y;
        float t2 = as4.z + ad4.z, t3 = as4.w + ad4.w;
        float tot = __expf(fmaxf(t0, 0.2f * t0)) * i0
                  + __expf(fmaxf(t1, 0.2f * t1)) * i1
                  + __expf(fmaxf(t2, 0.2f * t2)) * i2
                  + __expf(fmaxf(t3, 0.2f * t3)) * i3;
        unsigned long long enc = (1ull << 40) |
            (unsigned long long)(tot * POOL_SCALE + 0.5f);
        atomicAdd(pool + s, enc);
    }
}

// ---------- K5: node scores ----------
__global__ __launch_bounds__(256) void k_final(
    const unsigned long long* __restrict__ pool, const int* __restrict__ dirp,
    float* __restrict__ out)
{
    int i = blockIdx.x * 256 + threadIdx.x;
    if (i >= N_NODES) return;
    unsigned long long v = pool[i];
    unsigned int cnt = (unsigned int)(v >> 40);
    float val = (float)((double)(v & POOL_MASK) * (1.0 / (double)POOL_SCALE));
    int di = dirp[0];
    float dirf = (di >= -1000 && di <= 1000) ? (float)di : __int_as_float(di);
    float denom = (cnt > 1u) ? (float)cnt : 1.0f;
    out[(size_t)N_NODES * 64 + i] = dirf * val / denom;
}

// ---------- launch ----------
extern "C" void kernel_launch(void* const* d_in, const int* in_sizes, int n_in,
                              void* d_out, int out_size, void* d_ws, size_t ws_size,
                              hipStream_t stream)
{
    const float* x       = (const float*)d_in[0];
    const float* W       = (const float*)d_in[1];
    const float* att_src = (const float*)d_in[2];
    const float* att_dst = (const float*)d_in[3];
    const float* bias    = (const float*)d_in[4];
    const int*   ei      = (const int*)d_in[5];
    const int*   dirp    = (const int*)d_in[6];
    float* out = (float*)d_out;

    char* w = (char*)d_ws;
    size_t off = 0;
    auto alloc = [&](size_t bytes) -> void* {
        void* p = w + off;
        off = (off + bytes + 255) & ~(size_t)255;
        return p;
    };
    int* gcur = (int*)alloc((size_t)NBUCKET * sizeof(int));          // zeroed by k_gemm
    unsigned long long* pool = (unsigned long long*)alloc((size_t)N_NODES * sizeof(unsigned long long)); // zeroed by k_bucket
    float* a_s = (float*)alloc((size_t)N_NODES * 4 * sizeof(float));
    float* a_d = (float*)alloc((size_t)N_NODES * 4 * sizeof(float));
    int* cnt_dst = (int*)alloc((size_t)NODES_PAD * sizeof(int));
    unsigned int* binned = (unsigned int*)alloc((size_t)NBUCKET * BCAP * sizeof(unsigned int));
    unsigned short* slot = (unsigned short*)alloc((size_t)NODES_PAD * CAP * sizeof(unsigned short));
    unsigned short* H = (unsigned short*)alloc((size_t)N_NODES * 256 * sizeof(unsigned short));
    (void)ws_size; (void)in_sizes; (void)n_in; (void)out_size;

    k_gemm<<<(N_NODES + 63) / 64, 256, 0, stream>>>(x, W, att_src, att_dst, H, a_s, a_d, gcur);
    k_bin<<<BIN_BLOCKS, 256, 0, stream>>>(ei, gcur, binned);
    k_bucket<<<NBUCKET, 256, 0, stream>>>(binned, gcur, slot, cnt_dst, pool);
    k_gather<<<N_NODES / 4, 256, 0, stream>>>(H, slot, cnt_dst, a_s, a_d, bias, pool, out);
    k_final<<<(N_NODES + 255) / 256, 256, 0, stream>>>(pool, dirp, out);
}

// Round 11
// 334.271 us; speedup vs baseline: 1.3435x; 1.3435x over previous
//
#include <hip/hip_runtime.h>
#include <stdint.h>

#define N_NODES 50000
#define N_EDGES 1600000
#define IN_CH   128
#define OUT_CH  64
#define CAP     72            // per-node slot capacity; P(Poisson(32) >= 72) ~ 6e-18
#define NBUCKET 196           // bucket = dst >> 8  (49999>>8 = 195)
#define BCAP    10240         // per-bucket edge capacity incl. x4 pad slack (mean 9660)
#define BIN_BLOCKS 1000
#define EPB     1600          // edges per bin block; 1000*1600 = 1.6M exactly
#define BKCAP   32            // per-(block,bucket) LDS stage cap; mean 8.2, fallback safe
#define NODES_PAD (NBUCKET * 256)   // 50176
#define SENTINEL 0xFFFFFFFFu  // impossible packed edge: src<<16 with src<=49999

// ---------- small helpers ----------
__device__ __forceinline__ unsigned int f2bf(float f) {
    unsigned int u = __float_as_uint(f);
    u += 0x7fffu + ((u >> 16) & 1u);   // round-to-nearest-even
    return u >> 16;
}
__device__ __forceinline__ float lrelu(float v, float s) { return v > 0.f ? v : s * v; }

#define POOL_SCALE 268435456.0f        // 2^28 fixed-point for packed alpha-sum
#define POOL_MASK  ((1ull << 40) - 1ull)

// ---------- K1: H = x @ W[i] (bf16 out), a_s, a_d; block 0 zeroes gcur ----------
__global__ __launch_bounds__(256, 1) void k_gemm(
    const float* __restrict__ x, const float* __restrict__ W,
    const float* __restrict__ att_src, const float* __restrict__ att_dst,
    unsigned short* __restrict__ H, float* __restrict__ a_s, float* __restrict__ a_d,
    int* __restrict__ gcur)
{
    __shared__ __align__(16) unsigned char smem[64 * 264 * 2];  // 33792 B, overlaid
    float* sx = (float*)smem;                   // [64][129] fp32 x tile
    unsigned short* sh = (unsigned short*)smem; // [64][264] bf16 H tile

    const int tid  = threadIdx.x;
    const int lane = tid & 63;
    const int wv   = __builtin_amdgcn_readfirstlane(tid >> 6);
    const int row0 = blockIdx.x * 64;

    if (blockIdx.x == 0 && tid < NBUCKET) gcur[tid] = 0;   // replaces memset dispatch

    for (int idx = tid; idx < 64 * 32; idx += 256) {
        int r = idx >> 5, c4 = idx & 31;
        int row = row0 + r;
        float4 v = make_float4(0.f, 0.f, 0.f, 0.f);
        if (row < N_NODES) v = ((const float4*)(x + (size_t)row * IN_CH))[c4];
        float* p = sx + r * 129 + c4 * 4;
        p[0] = v.x; p[1] = v.y; p[2] = v.z; p[3] = v.w;
    }
    __syncthreads();

    float acc[64];
#pragma unroll
    for (int c = 0; c < 64; ++c) acc[c] = 0.f;

    const float* Wl = W + (size_t)wv * IN_CH * OUT_CH;   // uniform -> s_load
    const float* xrow = sx + lane * 129;
#pragma unroll 2
    for (int k = 0; k < IN_CH; ++k) {
        float xv = xrow[k];
        const float* Wk = Wl + k * OUT_CH;
#pragma unroll
        for (int c = 0; c < 64; ++c) acc[c] = fmaf(xv, Wk[c], acc[c]);
    }

    const float* As = att_src + wv * OUT_CH;
    const float* Ad = att_dst + wv * OUT_CH;
    float asv = 0.f, adv = 0.f;
#pragma unroll
    for (int c = 0; c < 64; ++c) { asv = fmaf(acc[c], As[c], asv); adv = fmaf(acc[c], Ad[c], adv); }
    int row = row0 + lane;
    if (row < N_NODES) { a_s[row * 4 + wv] = asv; a_d[row * 4 + wv] = adv; }

    __syncthreads();
    unsigned int* shp = (unsigned int*)sh;
#pragma unroll
    for (int c2 = 0; c2 < 32; ++c2) {
        unsigned int lo = f2bf(acc[c2 * 2]);
        unsigned int hi = f2bf(acc[c2 * 2 + 1]);
        shp[lane * 132 + wv * 32 + c2] = lo | (hi << 16);
    }
    __syncthreads();

    for (int idx = tid; idx < 64 * 32; idx += 256) {
        int r = idx >> 5, c8 = idx & 31;
        int row2 = row0 + r;
        if (row2 < N_NODES) {
            const uint4* srcp = (const uint4*)(sh + r * 264);
            ((uint4*)(H + (size_t)row2 * 256))[c8] = srcp[c8];
        }
    }
}

// ---------- K2: single-pass bin, LDS staging, ALIGNED uint4 flush ----------
__global__ __launch_bounds__(256) void k_bin(
    const int* __restrict__ ei, int* __restrict__ gcur,
    unsigned int* __restrict__ binned)
{
    __shared__ int lcnt[NBUCKET];
    __shared__ unsigned int stage[BKCAP * 256];   // [pos][bk], bank = bk%32
    const int tid = threadIdx.x;
    const int start = blockIdx.x * EPB;

    // self-detect int64 vs int32: odd 32-bit words all zero iff int64
    int probe = ei[2 * (start + tid) + 1];
    const int is64 = (__ballot(probe != 0) == 0ull) ? 1 : 0;

    for (int i = tid; i < NBUCKET; i += 256) lcnt[i] = 0;
    __syncthreads();

    for (int e = start + tid; e < start + EPB; e += 256) {
        int s = is64 ? ei[2 * (long long)e] : ei[e];
        int d = is64 ? ei[2 * ((long long)N_EDGES + e)] : ei[N_EDGES + e];
        int bk = d >> 8;
        unsigned int pk = ((unsigned int)s << 16) | (unsigned int)d;
        int pos = atomicAdd(&lcnt[bk], 1);
        if (pos < BKCAP) {
            stage[pos * 256 + bk] = pk;
        } else {                                   // rare fallback keeps x4 alignment
            int gi = atomicAdd(&gcur[bk], 4);
            if (gi + 3 < BCAP) {
                unsigned int* q = binned + bk * BCAP + gi;
                q[0] = pk; q[1] = SENTINEL; q[2] = SENTINEL; q[3] = SENTINEL;
            }
        }
    }
    __syncthreads();

    // one thread per bucket: reserve x4-aligned space, flush as 16B stores.
    // stage reads: thread bk hits bank bk%32 -> 2-way across wave (free).
    if (tid < NBUCKET) {
        int c = lcnt[tid];
        if (c > BKCAP) c = BKCAP;
        int cpad = (c + 3) & ~3;
        if (cpad) {
            int base = atomicAdd(&gcur[tid], cpad);
            if (base + cpad <= BCAP) {
                uint4* dst = (uint4*)(binned + tid * BCAP + base);  // base%4==0 -> 16B aligned
                for (int p = 0; p < c; p += 4) {
                    uint4 v;
                    v.x = stage[p * 256 + tid];
                    v.y = (p + 1 < c) ? stage[(p + 1) * 256 + tid] : SENTINEL;
                    v.z = (p + 2 < c) ? stage[(p + 2) * 256 + tid] : SENTINEL;
                    v.w = (p + 3 < c) ? stage[(p + 3) * 256 + tid] : SENTINEL;
                    dst[p >> 2] = v;
                }
            }
        }
    }
}

// ---------- K3: per-bucket placement in LDS, coalesced flush; zeroes pool ----------
__global__ __launch_bounds__(256) void k_bucket(
    const unsigned int* __restrict__ binned, const int* __restrict__ gcur,
    unsigned short* __restrict__ slot, int* __restrict__ cnt_dst,
    unsigned long long* __restrict__ pool)
{
    __shared__ unsigned short sl[256 * CAP];   // 36864 B slot tile (256 nodes)
    __shared__ int cnt[256];
    const int b = blockIdx.x;
    const int tid = threadIdx.x;
    cnt[tid] = 0;
    int pidx = b * 256 + tid;
    if (pidx < N_NODES) pool[pidx] = 0ull;     // replaces memset dispatch
    __syncthreads();

    int total = gcur[b];
    if (total > BCAP) total = BCAP;
    const unsigned int* src = binned + b * BCAP;
    for (int i = tid; i < total; i += 256) {
        unsigned int p = src[i];                 // coalesced
        if (p == SENTINEL) continue;             // alignment pad
        int local = p & 255;                     // d & 255 (bucket = d>>8)
        int pos = atomicAdd(&cnt[local], 1);     // LDS atomic — no fabric traffic
        if (pos < CAP) sl[local * CAP + pos] = (unsigned short)(p >> 16);
    }
    __syncthreads();

    uint4* g = (uint4*)(slot + (size_t)b * 256 * CAP);
    const uint4* l = (const uint4*)sl;
    for (int i = tid; i < 256 * CAP * 2 / 16; i += 256) g[i] = l[i];
    cnt_dst[b * 256 + tid] = cnt[tid];
}

// ---------- K4: per-dst-node gather, 16-edge MLP batches, fused src-pooling ----------
__global__ __launch_bounds__(256) void k_gather(
    const unsigned short* __restrict__ H, const unsigned short* __restrict__ slot,
    const int* __restrict__ cnt_dst,
    const float* __restrict__ a_s, const float* __restrict__ a_d,
    const float* __restrict__ bias, unsigned long long* __restrict__ pool,
    float* __restrict__ out)
{
    const int lane = threadIdx.x & 63;
    const int wv = __builtin_amdgcn_readfirstlane(threadIdx.x >> 6);
    const int node = blockIdx.x * 4 + wv;          // grid*4 == N_NODES exactly
    int deg = __builtin_amdgcn_readfirstlane(cnt_dst[node]);
    if (deg > CAP) deg = CAP;
    const int layer = lane >> 4;

    const float adv = a_d[node * 4 + layer];
    const float4* as4p = (const float4*)a_s;

    float ax = 0.f, ay = 0.f, az = 0.f, aw = 0.f, sumExp = 0.f;
    const uint2* Hp = (const uint2*)H + lane;      // lane's 8B of each 512B row

    auto body = [&](unsigned int s) {
        float4 as4 = as4p[s];                      // wave-uniform -> s_load_dwordx4
        float asv = (layer & 2) ? ((layer & 1) ? as4.w : as4.z)
                                : ((layer & 1) ? as4.y : as4.x);
        float t = asv + adv;
        float ew = __expf(fmaxf(t, 0.2f * t));     // lrelu+exp, 3 VALU
        uint2 hv = Hp[(size_t)s * 64];             // 512B/wave coalesced
        ax = fmaf(ew, __uint_as_float(hv.x << 16), ax);
        ay = fmaf(ew, __uint_as_float(hv.x & 0xffff0000u), ay);
        az = fmaf(ew, __uint_as_float(hv.y << 16), az);
        aw = fmaf(ew, __uint_as_float(hv.y & 0xffff0000u), aw);
        sumExp += ew;
    };

    const unsigned int* sp = (const unsigned int*)(slot + (size_t)node * CAP);
    const int npair = deg >> 1;
    int j2 = 0;
    for (; j2 + 8 <= npair; j2 += 8) {             // 16 edges in flight
        uint4 pa = *(const uint4*)(sp + j2);
        uint4 pb = *(const uint4*)(sp + j2 + 4);
        body(pa.x & 0xffffu); body(pa.x >> 16);
        body(pa.y & 0xffffu); body(pa.y >> 16);
        body(pa.z & 0xffffu); body(pa.z >> 16);
        body(pa.w & 0xffffu); body(pa.w >> 16);
        body(pb.x & 0xffffu); body(pb.x >> 16);
        body(pb.y & 0xffffu); body(pb.y >> 16);
        body(pb.z & 0xffffu); body(pb.z >> 16);
        body(pb.w & 0xffffu); body(pb.w >> 16);
    }
    for (; j2 + 4 <= npair; j2 += 4) {             // 8 edges
        uint4 p4 = *(const uint4*)(sp + j2);
        body(p4.x & 0xffffu); body(p4.x >> 16);
        body(p4.y & 0xffffu); body(p4.y >> 16);
        body(p4.z & 0xffffu); body(p4.z >> 16);
        body(p4.w & 0xffffu); body(p4.w >> 16);
    }
    for (; j2 < npair; ++j2) {
        unsigned int pr = sp[j2];
        body(pr & 0xffffu); body(pr >> 16);
    }
    if (deg & 1) body(sp[npair] & 0xffffu);

    float inv = 1.0f / (sumExp + 1e-16f);          // normalize once per node
    float4 b = ((const float4*)bias)[lane];
    float v0 = lrelu(fmaf(ax, inv, b.x), 0.01f);
    float v1 = lrelu(fmaf(ay, inv, b.y), 0.01f);
    float v2 = lrelu(fmaf(az, inv, b.z), 0.01f);
    float v3 = lrelu(fmaf(aw, inv, b.w), 0.01f);
    // sum the 4 layers: partners are lane ^ 16, lane ^ 32
    v0 += __shfl_xor(v0, 16); v0 += __shfl_xor(v0, 32);
    v1 += __shfl_xor(v1, 16); v1 += __shfl_xor(v1, 32);
    v2 += __shfl_xor(v2, 16); v2 += __shfl_xor(v2, 32);
    v3 += __shfl_xor(v3, 16); v3 += __shfl_xor(v3, 32);

    if (lane < 16) {
        ((float4*)(out + (size_t)node * 64))[lane] = make_float4(v0, v1, v2, v3);
    }

    // phase B: fused pooling — one packed u64 atomic per edge
    float i0 = 1.0f / (__shfl(sumExp,  0) + 1e-16f);
    float i1 = 1.0f / (__shfl(sumExp, 16) + 1e-16f);
    float i2 = 1.0f / (__shfl(sumExp, 32) + 1e-16f);
    float i3 = 1.0f / (__shfl(sumExp, 48) + 1e-16f);
    float4 ad4 = ((const float4*)a_d)[node];       // wave-uniform
    const unsigned short* s16 = slot + (size_t)node * CAP;
    for (int jj = lane; jj < deg; jj += 64) {
        int s = s16[jj];                           // coalesced 2B/lane
        float4 as4 = as4p[s];                      // 16B/lane gather (L2-hot)
        float t0 = as4.x + ad4.x, t1 = as4.y + ad4.y;
        float t2 = as4.z + ad4.z, t3 = as4.w + ad4.w;
        float tot = __expf(fmaxf(t0, 0.2f * t0)) * i0
                  + __expf(fmaxf(t1, 0.2f * t1)) * i1
                  + __expf(fmaxf(t2, 0.2f * t2)) * i2
                  + __expf(fmaxf(t3, 0.2f * t3)) * i3;
        unsigned long long enc = (1ull << 40) |
            (unsigned long long)(tot * POOL_SCALE + 0.5f);
        atomicAdd(pool + s, enc);
    }
}

// ---------- K5: node scores ----------
__global__ __launch_bounds__(256) void k_final(
    const unsigned long long* __restrict__ pool, const int* __restrict__ dirp,
    float* __restrict__ out)
{
    int i = blockIdx.x * 256 + threadIdx.x;
    if (i >= N_NODES) return;
    unsigned long long v = pool[i];
    unsigned int cnt = (unsigned int)(v >> 40);
    float val = (float)((double)(v & POOL_MASK) * (1.0 / (double)POOL_SCALE));
    int di = dirp[0];
    float dirf = (di >= -1000 && di <= 1000) ? (float)di : __int_as_float(di);
    float denom = (cnt > 1u) ? (float)cnt : 1.0f;
    out[(size_t)N_NODES * 64 + i] = dirf * val / denom;
}

// ---------- launch ----------
extern "C" void kernel_launch(void* const* d_in, const int* in_sizes, int n_in,
                              void* d_out, int out_size, void* d_ws, size_t ws_size,
                              hipStream_t stream)
{
    const float* x       = (const float*)d_in[0];
    const float* W       = (const float*)d_in[1];
    const float* att_src = (const float*)d_in[2];
    const float* att_dst = (const float*)d_in[3];
    const float* bias    = (const float*)d_in[4];
    const int*   ei      = (const int*)d_in[5];
    const int*   dirp    = (const int*)d_in[6];
    float* out = (float*)d_out;

    char* w = (char*)d_ws;
    size_t off = 0;
    auto alloc = [&](size_t bytes) -> void* {
        void* p = w + off;
        off = (off + bytes + 255) & ~(size_t)255;
        return p;
    };
    int* gcur = (int*)alloc((size_t)NBUCKET * sizeof(int));          // zeroed by k_gemm
    unsigned long long* pool = (unsigned long long*)alloc((size_t)N_NODES * sizeof(unsigned long long)); // zeroed by k_bucket
    float* a_s = (float*)alloc((size_t)N_NODES * 4 * sizeof(float));
    float* a_d = (float*)alloc((size_t)N_NODES * 4 * sizeof(float));
    int* cnt_dst = (int*)alloc((size_t)NODES_PAD * sizeof(int));
    unsigned int* binned = (unsigned int*)alloc((size_t)NBUCKET * BCAP * sizeof(unsigned int));
    unsigned short* slot = (unsigned short*)alloc((size_t)NODES_PAD * CAP * sizeof(unsigned short));
    unsigned short* H = (unsigned short*)alloc((size_t)N_NODES * 256 * sizeof(unsigned short));
    (void)ws_size; (void)in_sizes; (void)n_in; (void)out_size;

    k_gemm<<<(N_NODES + 63) / 64, 256, 0, stream>>>(x, W, att_src, att_dst, H, a_s, a_d, gcur);
    k_bin<<<BIN_BLOCKS, 256, 0, stream>>>(ei, gcur, binned);
    k_bucket<<<NBUCKET, 256, 0, stream>>>(binned, gcur, slot, cnt_dst, pool);
    k_gather<<<N_NODES / 4, 256, 0, stream>>>(H, slot, cnt_dst, a_s, a_d, bias, pool, out);
    k_final<<<(N_NODES + 255) / 256, 256, 0, stream>>>(pool, dirp, out);
}

// Round 12
// 317.038 us; speedup vs baseline: 1.4165x; 1.0544x over previous
//
#include <hip/hip_runtime.h>
#include <stdint.h>

#define N_NODES 50000
#define N_EDGES 1600000
#define IN_CH   128
#define OUT_CH  64
#define CAP     72            // per-node slot capacity; P(Poisson(32) >= 72) ~ 6e-18
#define NBUCKET 196           // bucket = dst >> 8  (49999>>8 = 195)
#define BCAP    10240         // per-bucket edge capacity incl. x4 pad slack (mean 9660)
#define MB      782           // merged blocks: ceil(50000/64)
#define EPB2    2047          // edges per merged block; 782*2047 = 1600754 >= E
#define BKCAP   32            // per-(block,bucket) LDS stage cap; mean 10.4, fallback safe
#define NODES_PAD (NBUCKET * 256)   // 50176
#define SENTINEL 0xFFFFFFFFu  // impossible packed edge: src<<16 with src<=49999

// ---------- small helpers ----------
__device__ __forceinline__ unsigned int f2bf(float f) {
    unsigned int u = __float_as_uint(f);
    u += 0x7fffu + ((u >> 16) & 1u);   // round-to-nearest-even
    return u >> 16;
}
__device__ __forceinline__ float lrelu(float v, float s) { return v > 0.f ? v : s * v; }

#define POOL_SCALE 268435456.0f        // 2^28 fixed-point for packed alpha-sum
#define POOL_MASK  ((1ull << 40) - 1ull)

// ---------- K1 (merged): GEMM phase, then bin phase (sequential, LDS reused) ----------
__global__ __launch_bounds__(256, 1) void k_gemmbin(
    const float* __restrict__ x, const float* __restrict__ W,
    const float* __restrict__ att_src, const float* __restrict__ att_dst,
    unsigned short* __restrict__ H, float* __restrict__ a_s, float* __restrict__ a_d,
    const int* __restrict__ ei, int* __restrict__ gcur,
    unsigned int* __restrict__ binned)
{
    __shared__ __align__(16) unsigned char smem[64 * 264 * 2];  // 33792 B, overlaid
    float* sx = (float*)smem;                   // [64][129] fp32 x tile
    unsigned short* sh = (unsigned short*)smem; // [64][264] bf16 H tile

    const int tid  = threadIdx.x;
    const int lane = tid & 63;
    const int wv   = __builtin_amdgcn_readfirstlane(tid >> 6);
    const int row0 = blockIdx.x * 64;

    // ======== phase 1: GEMM (identical to proven k_gemm) ========
    for (int idx = tid; idx < 64 * 32; idx += 256) {
        int r = idx >> 5, c4 = idx & 31;
        int row = row0 + r;
        float4 v = make_float4(0.f, 0.f, 0.f, 0.f);
        if (row < N_NODES) v = ((const float4*)(x + (size_t)row * IN_CH))[c4];
        float* p = sx + r * 129 + c4 * 4;
        p[0] = v.x; p[1] = v.y; p[2] = v.z; p[3] = v.w;
    }
    __syncthreads();

    float acc[64];
#pragma unroll
    for (int c = 0; c < 64; ++c) acc[c] = 0.f;

    const float* Wl = W + (size_t)wv * IN_CH * OUT_CH;   // uniform -> s_load
    const float* xrow = sx + lane * 129;
#pragma unroll 2
    for (int k = 0; k < IN_CH; ++k) {
        float xv = xrow[k];
        const float* Wk = Wl + k * OUT_CH;
#pragma unroll
        for (int c = 0; c < 64; ++c) acc[c] = fmaf(xv, Wk[c], acc[c]);
    }

    const float* As = att_src + wv * OUT_CH;
    const float* Ad = att_dst + wv * OUT_CH;
    float asv = 0.f, adv = 0.f;
#pragma unroll
    for (int c = 0; c < 64; ++c) { asv = fmaf(acc[c], As[c], asv); adv = fmaf(acc[c], Ad[c], adv); }
    int row = row0 + lane;
    if (row < N_NODES) { a_s[row * 4 + wv] = asv; a_d[row * 4 + wv] = adv; }

    __syncthreads();
    unsigned int* shp = (unsigned int*)sh;
#pragma unroll
    for (int c2 = 0; c2 < 32; ++c2) {
        unsigned int lo = f2bf(acc[c2 * 2]);
        unsigned int hi = f2bf(acc[c2 * 2 + 1]);
        shp[lane * 132 + wv * 32 + c2] = lo | (hi << 16);
    }
    __syncthreads();

    for (int idx = tid; idx < 64 * 32; idx += 256) {
        int r = idx >> 5, c8 = idx & 31;
        int row2 = row0 + r;
        if (row2 < N_NODES) {
            const uint4* srcp = (const uint4*)(sh + r * 264);
            ((uint4*)(H + (size_t)row2 * 256))[c8] = srcp[c8];
        }
    }
    __syncthreads();

    // ======== phase 2: bin edges into dst-buckets (acc[] dead, LDS reused) ========
    int* lcnt = (int*)smem;                               // [196]
    unsigned int* stage = (unsigned int*)(smem + 1024);   // [BKCAP][256]
    const int start = blockIdx.x * EPB2;
    const int end = (start + EPB2 < N_EDGES) ? start + EPB2 : N_EDGES;

    // self-detect int64 vs int32: odd 32-bit words all zero iff int64
    int probe = ei[2 * (start + tid) + 1];
    const int is64 = (__ballot(probe != 0) == 0ull) ? 1 : 0;

    for (int i = tid; i < NBUCKET; i += 256) lcnt[i] = 0;
    __syncthreads();

    for (int e = start + tid; e < end; e += 256) {
        int s = is64 ? ei[2 * (long long)e] : ei[e];
        int d = is64 ? ei[2 * ((long long)N_EDGES + e)] : ei[N_EDGES + e];
        int bk = d >> 8;
        unsigned int pk = ((unsigned int)s << 16) | (unsigned int)d;
        int pos = atomicAdd(&lcnt[bk], 1);
        if (pos < BKCAP) {
            stage[pos * 256 + bk] = pk;
        } else {                                   // rare fallback keeps x4 alignment
            int gi = atomicAdd(&gcur[bk], 4);
            if (gi + 3 < BCAP) {
                unsigned int* q = binned + bk * BCAP + gi;
                q[0] = pk; q[1] = SENTINEL; q[2] = SENTINEL; q[3] = SENTINEL;
            }
        }
    }
    __syncthreads();

    // one thread per bucket: reserve x4-aligned space, flush as 16B stores
    if (tid < NBUCKET) {
        int c = lcnt[tid];
        if (c > BKCAP) c = BKCAP;
        int cpad = (c + 3) & ~3;
        if (cpad) {
            int base = atomicAdd(&gcur[tid], cpad);
            if (base + cpad <= BCAP) {
                uint4* dst = (uint4*)(binned + tid * BCAP + base);  // base%4==0
                for (int p = 0; p < c; p += 4) {
                    uint4 v;
                    v.x = stage[p * 256 + tid];
                    v.y = (p + 1 < c) ? stage[(p + 1) * 256 + tid] : SENTINEL;
                    v.z = (p + 2 < c) ? stage[(p + 2) * 256 + tid] : SENTINEL;
                    v.w = (p + 3 < c) ? stage[(p + 3) * 256 + tid] : SENTINEL;
                    dst[p >> 2] = v;
                }
            }
        }
    }
}

// ---------- K2: per-bucket placement in LDS, coalesced flush; zeroes pool ----------
__global__ __launch_bounds__(256) void k_bucket(
    const unsigned int* __restrict__ binned, const int* __restrict__ gcur,
    unsigned short* __restrict__ slot, int* __restrict__ cnt_dst,
    unsigned long long* __restrict__ pool)
{
    __shared__ unsigned short sl[256 * CAP];   // 36864 B slot tile (256 nodes)
    __shared__ int cnt[256];
    const int b = blockIdx.x;
    const int tid = threadIdx.x;
    cnt[tid] = 0;
    int pidx = b * 256 + tid;
    if (pidx < N_NODES) pool[pidx] = 0ull;     // replaces memset dispatch
    __syncthreads();

    int total = gcur[b];
    if (total > BCAP) total = BCAP;
    const unsigned int* src = binned + b * BCAP;
    for (int i = tid; i < total; i += 256) {
        unsigned int p = src[i];                 // coalesced
        if (p == SENTINEL) continue;             // alignment pad
        int local = p & 255;                     // d & 255 (bucket = d>>8)
        int pos = atomicAdd(&cnt[local], 1);     // LDS atomic — no fabric traffic
        if (pos < CAP) sl[local * CAP + pos] = (unsigned short)(p >> 16);
    }
    __syncthreads();

    uint4* g = (uint4*)(slot + (size_t)b * 256 * CAP);
    const uint4* l = (const uint4*)sl;
    for (int i = tid; i < 256 * CAP * 2 / 16; i += 256) g[i] = l[i];
    cnt_dst[b * 256 + tid] = cnt[tid];
}

// ---------- K3: gather — lane-parallel ew precompute into LDS, then MLP loop ----------
__global__ __launch_bounds__(256) void k_gather(
    const unsigned short* __restrict__ H, const unsigned short* __restrict__ slot,
    const int* __restrict__ cnt_dst,
    const float* __restrict__ a_s, const float* __restrict__ a_d,
    const float* __restrict__ bias, unsigned long long* __restrict__ pool,
    float* __restrict__ out)
{
    __shared__ __align__(16) float ewlds[4][CAP * 4];   // per-wave ew stash, 4608 B

    const int lane = threadIdx.x & 63;
    const int wv = __builtin_amdgcn_readfirstlane(threadIdx.x >> 6);
    const int node = blockIdx.x * 4 + wv;          // grid*4 == N_NODES exactly
    int deg = __builtin_amdgcn_readfirstlane(cnt_dst[node]);
    if (deg > CAP) deg = CAP;
    const int layer = lane >> 4;
    float* ewl = ewlds[wv];

    const float4* as4p = (const float4*)a_s;
    const unsigned short* s16 = slot + (size_t)node * CAP;
    const float4 ad4 = ((const float4*)a_d)[node];  // wave-uniform

    // ---- precompute: all <=72 edges' 4-layer exp-weights, lane-parallel ----
    // 2 iterations x 4 exps/lane replaces 1 redundant exp per edge per 64 lanes
#pragma unroll
    for (int base = 0; base < CAP; base += 64) {
        int j = base + lane;
        if (j < deg) {
            int s = s16[j];                        // coalesced 2B/lane
            float4 as4 = as4p[s];                  // 16B/lane gather (L2-hot, 800KB tbl)
            float t0 = as4.x + ad4.x, t1 = as4.y + ad4.y;
            float t2 = as4.z + ad4.z, t3 = as4.w + ad4.w;
            float4 e4;
            e4.x = __expf(fmaxf(t0, 0.2f * t0));
            e4.y = __expf(fmaxf(t1, 0.2f * t1));
            e4.z = __expf(fmaxf(t2, 0.2f * t2));
            e4.w = __expf(fmaxf(t3, 0.2f * t3));
            *(float4*)(ewl + j * 4) = e4;          // wave-private: no barrier needed
        }
    }

    // ---- phase A: feature accumulation + sumExp (no exp, no select) ----
    float ax = 0.f, ay = 0.f, az = 0.f, aw = 0.f, sumExp = 0.f;
    const uint2* Hp = (const uint2*)H + lane;      // lane's 8B of each 512B row

    auto body = [&](unsigned int s, int j) {
        float ew = ewl[j * 4 + layer];             // ds_read_b32 broadcast
        uint2 hv = Hp[(size_t)s * 64];             // 512B/wave coalesced
        ax = fmaf(ew, __uint_as_float(hv.x << 16), ax);
        ay = fmaf(ew, __uint_as_float(hv.x & 0xffff0000u), ay);
        az = fmaf(ew, __uint_as_float(hv.y << 16), az);
        aw = fmaf(ew, __uint_as_float(hv.y & 0xffff0000u), aw);
        sumExp += ew;
    };

    const unsigned int* sp = (const unsigned int*)s16;
    const int npair = deg >> 1;
    int j2 = 0;
    for (; j2 + 8 <= npair; j2 += 8) {             // 16 edges in flight
        uint4 pa = *(const uint4*)(sp + j2);
        uint4 pb = *(const uint4*)(sp + j2 + 4);
        body(pa.x & 0xffffu, 2*j2+0); body(pa.x >> 16, 2*j2+1);
        body(pa.y & 0xffffu, 2*j2+2); body(pa.y >> 16, 2*j2+3);
        body(pa.z & 0xffffu, 2*j2+4); body(pa.z >> 16, 2*j2+5);
        body(pa.w & 0xffffu, 2*j2+6); body(pa.w >> 16, 2*j2+7);
        body(pb.x & 0xffffu, 2*j2+8); body(pb.x >> 16, 2*j2+9);
        body(pb.y & 0xffffu, 2*j2+10); body(pb.y >> 16, 2*j2+11);
        body(pb.z & 0xffffu, 2*j2+12); body(pb.z >> 16, 2*j2+13);
        body(pb.w & 0xffffu, 2*j2+14); body(pb.w >> 16, 2*j2+15);
    }
    for (; j2 + 4 <= npair; j2 += 4) {             // 8 edges
        uint4 p4 = *(const uint4*)(sp + j2);
        body(p4.x & 0xffffu, 2*j2+0); body(p4.x >> 16, 2*j2+1);
        body(p4.y & 0xffffu, 2*j2+2); body(p4.y >> 16, 2*j2+3);
        body(p4.z & 0xffffu, 2*j2+4); body(p4.z >> 16, 2*j2+5);
        body(p4.w & 0xffffu, 2*j2+6); body(p4.w >> 16, 2*j2+7);
    }
    for (; j2 < npair; ++j2) {
        unsigned int pr = sp[j2];
        body(pr & 0xffffu, 2*j2); body(pr >> 16, 2*j2+1);
    }
    if (deg & 1) body(sp[npair] & 0xffffu, deg - 1);

    float inv = 1.0f / (sumExp + 1e-16f);          // normalize once per node
    float4 b = ((const float4*)bias)[lane];
    float v0 = lrelu(fmaf(ax, inv, b.x), 0.01f);
    float v1 = lrelu(fmaf(ay, inv, b.y), 0.01f);
    float v2 = lrelu(fmaf(az, inv, b.z), 0.01f);
    float v3 = lrelu(fmaf(aw, inv, b.w), 0.01f);
    // sum the 4 layers: partners are lane ^ 16, lane ^ 32
    v0 += __shfl_xor(v0, 16); v0 += __shfl_xor(v0, 32);
    v1 += __shfl_xor(v1, 16); v1 += __shfl_xor(v1, 32);
    v2 += __shfl_xor(v2, 16); v2 += __shfl_xor(v2, 32);
    v3 += __shfl_xor(v3, 16); v3 += __shfl_xor(v3, 32);

    if (lane < 16) {
        ((float4*)(out + (size_t)node * 64))[lane] = make_float4(v0, v1, v2, v3);
    }

    // phase B: fused pooling — LDS ews, one packed u64 atomic per edge
    float i0 = 1.0f / (__shfl(sumExp,  0) + 1e-16f);
    float i1 = 1.0f / (__shfl(sumExp, 16) + 1e-16f);
    float i2 = 1.0f / (__shfl(sumExp, 32) + 1e-16f);
    float i3 = 1.0f / (__shfl(sumExp, 48) + 1e-16f);
    for (int jj = lane; jj < deg; jj += 64) {
        int s = s16[jj];                           // coalesced 2B/lane
        float4 e4 = *(const float4*)(ewl + jj * 4);   // ds_read_b128, stashed
        float tot = e4.x * i0 + e4.y * i1 + e4.z * i2 + e4.w * i3;
        unsigned long long enc = (1ull << 40) |
            (unsigned long long)(tot * POOL_SCALE + 0.5f);
        atomicAdd(pool + s, enc);
    }
}

// ---------- K4: node scores ----------
__global__ __launch_bounds__(256) void k_final(
    const unsigned long long* __restrict__ pool, const int* __restrict__ dirp,
    float* __restrict__ out)
{
    int i = blockIdx.x * 256 + threadIdx.x;
    if (i >= N_NODES) return;
    unsigned long long v = pool[i];
    unsigned int cnt = (unsigned int)(v >> 40);
    float val = (float)((double)(v & POOL_MASK) * (1.0 / (double)POOL_SCALE));
    int di = dirp[0];
    float dirf = (di >= -1000 && di <= 1000) ? (float)di : __int_as_float(di);
    float denom = (cnt > 1u) ? (float)cnt : 1.0f;
    out[(size_t)N_NODES * 64 + i] = dirf * val / denom;
}

// ---------- launch ----------
extern "C" void kernel_launch(void* const* d_in, const int* in_sizes, int n_in,
                              void* d_out, int out_size, void* d_ws, size_t ws_size,
                              hipStream_t stream)
{
    const float* x       = (const float*)d_in[0];
    const float* W       = (const float*)d_in[1];
    const float* att_src = (const float*)d_in[2];
    const float* att_dst = (const float*)d_in[3];
    const float* bias    = (const float*)d_in[4];
    const int*   ei      = (const int*)d_in[5];
    const int*   dirp    = (const int*)d_in[6];
    float* out = (float*)d_out;

    char* w = (char*)d_ws;
    size_t off = 0;
    auto alloc = [&](size_t bytes) -> void* {
        void* p = w + off;
        off = (off + bytes + 255) & ~(size_t)255;
        return p;
    };
    int* gcur = (int*)alloc((size_t)NBUCKET * sizeof(int));          // zeroed by memset
    unsigned long long* pool = (unsigned long long*)alloc((size_t)N_NODES * sizeof(unsigned long long)); // zeroed by k_bucket
    float* a_s = (float*)alloc((size_t)N_NODES * 4 * sizeof(float));
    float* a_d = (float*)alloc((size_t)N_NODES * 4 * sizeof(float));
    int* cnt_dst = (int*)alloc((size_t)NODES_PAD * sizeof(int));
    unsigned int* binned = (unsigned int*)alloc((size_t)NBUCKET * BCAP * sizeof(unsigned int));
    unsigned short* slot = (unsigned short*)alloc((size_t)NODES_PAD * CAP * sizeof(unsigned short));
    unsigned short* H = (unsigned short*)alloc((size_t)N_NODES * 256 * sizeof(unsigned short));
    (void)ws_size; (void)in_sizes; (void)n_in; (void)out_size;

    hipMemsetAsync(gcur, 0, NBUCKET * sizeof(int), stream);
    k_gemmbin<<<MB, 256, 0, stream>>>(x, W, att_src, att_dst, H, a_s, a_d, ei, gcur, binned);
    k_bucket<<<NBUCKET, 256, 0, stream>>>(binned, gcur, slot, cnt_dst, pool);
    k_gather<<<N_NODES / 4, 256, 0, stream>>>(H, slot, cnt_dst, a_s, a_d, bias, pool, out);
    k_final<<<(N_NODES + 255) / 256, 256, 0, stream>>>(pool, dirp, out);
}